// Round 1
// 265.879 us; speedup vs baseline: 1.0396x; 1.0396x over previous
//
#include <hip/hip_runtime.h>
#include <cstdint>
#include <cstddef>

// ---------- types / helpers ----------
typedef float f32x4 __attribute__((ext_vector_type(4)));
typedef __bf16 bf16x8 __attribute__((ext_vector_type(8)));

__device__ __forceinline__ float b2f(unsigned short u) {
    union { unsigned int i; float f; } z; z.i = ((unsigned int)u) << 16; return z.f;
}
__device__ __forceinline__ unsigned short f2b(float f) {
    union { float f; unsigned int i; } z; z.f = f;
    unsigned int x = z.i;
    return (unsigned short)((x + 0x7FFFu + ((x >> 16) & 1u)) >> 16);
}

static constexpr int C = 128;
static constexpr int NP = 16384;      // H*W
static constexpr int NH = 8;

// ---------- weight pack: fp32 -> bf16 ----------
struct Ptr11 { const float* p[11]; };
__constant__ int kWN[11]   = {128, 128, 8, 49152, 3456, 16384, 128, 128, 65536, 4608, 32768};
__constant__ int kWOff[11] = {0, 128, 256, 272, 49424, 52880, 69264, 69392, 69520, 135056, 139664};
static constexpr int kWTotal = 172432;

__global__ __launch_bounds__(256)
void cvt_w_kernel(Ptr11 P, unsigned short* __restrict__ dst)
{
    int seg = blockIdx.y;
    int n = kWN[seg];
    int i = blockIdx.x * 256 + threadIdx.x;
    if (i >= n) return;
    dst[kWOff[seg] + i] = f2b(P.p[seg][i]);
}

// ---------- shared GEMM core: full K=128 tile in LDS, chunked Cout ----------
// Bs[k][n] bf16, 128x128. A-frag from global W (L2-hot), B-frag scalar LDS reads.
// Epilogue: bf16 store. acc D-layout: row co = quad*4+r, col n = ln16 (verified).
template <int COUT>
__device__ __forceinline__ void gemm_core_128(
    const unsigned short (*Bs)[128],
    const unsigned short* __restrict__ W,
    unsigned short* __restrict__ OutB,   // already + b*COUT*NP
    int n0, int tid)
{
    const int lane = tid & 63;
    const int wid  = tid >> 6;
    const int ln16 = lane & 15, quad = lane >> 4;
    const int wy = wid >> 1, wx = wid & 1;
    for (int cc = 0; cc < COUT / 128; ++cc) {
        const int m0 = cc * 128;
        f32x4 acc[4][4];
        #pragma unroll
        for (int i = 0; i < 4; ++i)
            #pragma unroll
            for (int j = 0; j < 4; ++j) acc[i][j] = f32x4{0.f, 0.f, 0.f, 0.f};

        #pragma unroll
        for (int k0 = 0; k0 < 128; k0 += 32) {
            bf16x8 afr[4], bfr[4];
            #pragma unroll
            for (int mt = 0; mt < 4; ++mt) {
                int m = m0 + wy * 64 + mt * 16 + ln16;
                uint4 v = *(const uint4*)(W + (size_t)m * 128 + k0 + quad * 8);
                afr[mt] = *(bf16x8*)&v;
            }
            #pragma unroll
            for (int nt = 0; nt < 4; ++nt) {
                int n = wx * 64 + nt * 16 + ln16;
                union { bf16x8 v; unsigned short u[8]; } tmp;
                #pragma unroll
                for (int j = 0; j < 8; ++j) tmp.u[j] = Bs[k0 + quad * 8 + j][n];
                bfr[nt] = tmp.v;
            }
            #pragma unroll
            for (int mt = 0; mt < 4; ++mt)
                #pragma unroll
                for (int nt = 0; nt < 4; ++nt)
                    acc[mt][nt] = __builtin_amdgcn_mfma_f32_16x16x32_bf16(
                        afr[mt], bfr[nt], acc[mt][nt], 0, 0, 0);
        }
        #pragma unroll
        for (int mt = 0; mt < 4; ++mt)
            #pragma unroll
            for (int nt = 0; nt < 4; ++nt) {
                int co0 = m0 + wy * 64 + mt * 16 + quad * 4;
                int n = n0 + wx * 64 + nt * 16 + ln16;
                #pragma unroll
                for (int r = 0; r < 4; ++r)
                    OutB[(size_t)(co0 + r) * NP + n] = f2b(acc[mt][nt][r]);
            }
    }
}

// ---------- fused LN(channel) + 1x1-conv GEMM ----------
// Block owns 128 pixels (one image row) x all 128 channels: LN stats in-block.
// thread t: pxg = t&31 (4 px), cseg = t>>5 (16 ch). Holds its 64 fp32 in regs.
template <int COUT>
__global__ __launch_bounds__(256)
void lngemm_kernel(const float* __restrict__ x,              // (nb, C, NP) fp32
                   const unsigned short* __restrict__ lg,    // ln gamma bf16
                   const unsigned short* __restrict__ lb,    // ln beta bf16
                   const unsigned short* __restrict__ W,     // (COUT, 128) bf16
                   unsigned short* __restrict__ Out)         // (nb, COUT, NP) bf16
{
    __shared__ unsigned short Bs[128][128];
    __shared__ float Ssum[8][128], Ssq[8][128], Mu[128], Rs[128];
    const int tid = threadIdx.x;
    const int b = blockIdx.y;
    const int n0 = blockIdx.x * 128;
    const int pxg = tid & 31;
    const int cseg = tid >> 5;
    const float* xb = x + (size_t)b * C * NP + n0 + pxg * 4;

    f32x4 hv[16];
    f32x4 vs = f32x4{0.f, 0.f, 0.f, 0.f}, vq = f32x4{0.f, 0.f, 0.f, 0.f};
    #pragma unroll
    for (int i = 0; i < 16; ++i) {
        f32x4 v = *(const f32x4*)(xb + (size_t)(cseg * 16 + i) * NP);
        hv[i] = v; vs += v; vq += v * v;
    }
    #pragma unroll
    for (int j = 0; j < 4; ++j) {
        Ssum[cseg][pxg * 4 + j] = vs[j];
        Ssq[cseg][pxg * 4 + j]  = vq[j];
    }
    __syncthreads();
    if (tid < 128) {
        float s = 0.f, q = 0.f;
        #pragma unroll
        for (int e = 0; e < 8; ++e) { s += Ssum[e][tid]; q += Ssq[e][tid]; }
        float mu = s * (1.f / 128.f);
        float var = q * (1.f / 128.f) - mu * mu;
        Mu[tid] = mu;
        Rs[tid] = rsqrtf(fmaxf(var, 0.f) + 1e-5f);
    }
    __syncthreads();
    f32x4 mu4 = *(const f32x4*)(&Mu[pxg * 4]);
    f32x4 rs4 = *(const f32x4*)(&Rs[pxg * 4]);
    #pragma unroll
    for (int i = 0; i < 16; ++i) {
        int c = cseg * 16 + i;
        float gw = b2f(lg[c]), bw = b2f(lb[c]);
        union { uint2 v; unsigned short u[4]; } o;
        #pragma unroll
        for (int j = 0; j < 4; ++j)
            o.u[j] = f2b((hv[i][j] - mu4[j]) * rs4[j] * gw + bw);
        *(uint2*)(&Bs[c][pxg * 4]) = o.v;
    }
    __syncthreads();
    gemm_core_128<COUT>(Bs, W, Out + (size_t)b * COUT * NP, n0, tid);
}

// ---------- plain bf16 GEMM, full-K staged once, chunked Cout ----------
template <int COUT>
__global__ __launch_bounds__(256)
void gemm_bf16_kernel(const unsigned short* __restrict__ W,   // (COUT,128) bf16
                      const unsigned short* __restrict__ X,   // (nb,128,NP) bf16
                      unsigned short* __restrict__ Out)       // (nb,COUT,NP) bf16
{
    __shared__ unsigned short Bs[128][128];
    const int tid = threadIdx.x;
    const int b = blockIdx.y;
    const int n0 = blockIdx.x * 128;
    const unsigned short* Xb = X + (size_t)b * 128 * NP;
    #pragma unroll
    for (int r = 0; r < 8; ++r) {
        int flat = tid + r * 256;
        int kk = flat >> 4, nn = (flat & 15) * 8;
        *(uint4*)(&Bs[kk][nn]) = *(const uint4*)(Xb + (size_t)kk * NP + n0 + nn);
    }
    __syncthreads();
    gemm_core_128<COUT>(Bs, W, Out + (size_t)b * COUT * NP, n0, tid);
}

// ---------- proj GEMM + fp32 residual + fused LN2 -> y2 bf16 ----------
__global__ __launch_bounds__(256)
void projln_kernel(const unsigned short* __restrict__ W,     // (128,128) proj bf16
                   const unsigned short* __restrict__ Xin,   // y bf16 (nb,128,NP)
                   const float* __restrict__ Res,            // x fp32
                   float* __restrict__ Xmid,                  // trunk out fp32
                   const unsigned short* __restrict__ lg,    // ln2 gamma
                   const unsigned short* __restrict__ lb,    // ln2 beta
                   unsigned short* __restrict__ Y2)          // bf16 LN2 out
{
    __shared__ unsigned short Bs[128][128];
    __shared__ float RedS[2][128], RedQ[2][128], Mu[128], Rs[128];
    const int tid = threadIdx.x;
    const int b = blockIdx.y;
    const int n0 = blockIdx.x * 128;
    const unsigned short* Xb = Xin + (size_t)b * 128 * NP;
    #pragma unroll
    for (int r = 0; r < 8; ++r) {
        int flat = tid + r * 256;
        int kk = flat >> 4, nn = (flat & 15) * 8;
        *(uint4*)(&Bs[kk][nn]) = *(const uint4*)(Xb + (size_t)kk * NP + n0 + nn);
    }
    __syncthreads();

    const int lane = tid & 63, wid = tid >> 6;
    const int ln16 = lane & 15, quad = lane >> 4;
    const int wy = wid >> 1, wx = wid & 1;

    f32x4 acc[4][4];
    #pragma unroll
    for (int i = 0; i < 4; ++i)
        #pragma unroll
        for (int j = 0; j < 4; ++j) acc[i][j] = f32x4{0.f, 0.f, 0.f, 0.f};

    #pragma unroll
    for (int k0 = 0; k0 < 128; k0 += 32) {
        bf16x8 afr[4], bfr[4];
        #pragma unroll
        for (int mt = 0; mt < 4; ++mt) {
            int m = wy * 64 + mt * 16 + ln16;
            uint4 v = *(const uint4*)(W + (size_t)m * 128 + k0 + quad * 8);
            afr[mt] = *(bf16x8*)&v;
        }
        #pragma unroll
        for (int nt = 0; nt < 4; ++nt) {
            int n = wx * 64 + nt * 16 + ln16;
            union { bf16x8 v; unsigned short u[8]; } tmp;
            #pragma unroll
            for (int j = 0; j < 8; ++j) tmp.u[j] = Bs[k0 + quad * 8 + j][n];
            bfr[nt] = tmp.v;
        }
        #pragma unroll
        for (int mt = 0; mt < 4; ++mt)
            #pragma unroll
            for (int nt = 0; nt < 4; ++nt)
                acc[mt][nt] = __builtin_amdgcn_mfma_f32_16x16x32_bf16(
                    afr[mt], bfr[nt], acc[mt][nt], 0, 0, 0);
    }

    // pass A: trunk = Res + acc -> Xmid, keep trunk in acc, per-pixel partials
    size_t base = (size_t)b * 128 * NP;
    float ps[4] = {0.f, 0.f, 0.f, 0.f}, pq[4] = {0.f, 0.f, 0.f, 0.f};
    #pragma unroll
    for (int mt = 0; mt < 4; ++mt)
        #pragma unroll
        for (int nt = 0; nt < 4; ++nt) {
            int co0 = wy * 64 + mt * 16 + quad * 4;
            int n = n0 + wx * 64 + nt * 16 + ln16;
            #pragma unroll
            for (int r = 0; r < 4; ++r) {
                size_t idx = base + (size_t)(co0 + r) * NP + n;
                float t = Res[idx] + acc[mt][nt][r];
                Xmid[idx] = t;
                acc[mt][nt][r] = t;
                ps[nt] += t; pq[nt] += t * t;
            }
        }
    #pragma unroll
    for (int nt = 0; nt < 4; ++nt) {
        ps[nt] += __shfl_xor(ps[nt], 16, 64); ps[nt] += __shfl_xor(ps[nt], 32, 64);
        pq[nt] += __shfl_xor(pq[nt], 16, 64); pq[nt] += __shfl_xor(pq[nt], 32, 64);
    }
    if (quad == 0) {
        #pragma unroll
        for (int nt = 0; nt < 4; ++nt) {
            int nn = wx * 64 + nt * 16 + ln16;
            RedS[wy][nn] = ps[nt]; RedQ[wy][nn] = pq[nt];
        }
    }
    __syncthreads();
    if (tid < 128) {
        float s = RedS[0][tid] + RedS[1][tid];
        float q = RedQ[0][tid] + RedQ[1][tid];
        float mu = s * (1.f / 128.f);
        float var = q * (1.f / 128.f) - mu * mu;
        Mu[tid] = mu; Rs[tid] = rsqrtf(fmaxf(var, 0.f) + 1e-5f);
    }
    __syncthreads();

    // pass B: y2 = (trunk - mu)*rs*g + b
    #pragma unroll
    for (int mt = 0; mt < 4; ++mt) {
        int co0 = wy * 64 + mt * 16 + quad * 4;
        union { uint2 v; unsigned short u[4]; } gv, bv;
        gv.v = *(const uint2*)(lg + co0);
        bv.v = *(const uint2*)(lb + co0);
        float gw[4], bw[4];
        #pragma unroll
        for (int r = 0; r < 4; ++r) { gw[r] = b2f(gv.u[r]); bw[r] = b2f(bv.u[r]); }
        #pragma unroll
        for (int nt = 0; nt < 4; ++nt) {
            int nn = wx * 64 + nt * 16 + ln16;
            float mu = Mu[nn], rs = Rs[nn];
            int n = n0 + nn;
            #pragma unroll
            for (int r = 0; r < 4; ++r) {
                size_t idx = base + (size_t)(co0 + r) * NP + n;
                Y2[idx] = f2b((acc[mt][nt][r] - mu) * rs * gw[r] + bw[r]);
            }
        }
    }
}

// ---------- legacy per-k-step GEMM (kept for g2: K=256, fp32 residual epi) ----------
template <int K, int EPI>
__global__ __launch_bounds__(256)
void gemm_pconv(const unsigned short* __restrict__ W,   // (Cout, K) bf16
                const unsigned short* __restrict__ X,   // (nb, K, NP) bf16
                void* __restrict__ Out,                 // (nb, Cout, NP)
                const float* __restrict__ Res,          // fp32 residual or null
                int Cout)
{
    __shared__ unsigned short Bs[32][128];
    const int tid = threadIdx.x;
    const int b = blockIdx.z;
    const int n0 = blockIdx.x * 128;
    const int m0 = blockIdx.y * 128;
    const unsigned short* Xb = X + (size_t)b * K * NP;
    const int wid = tid >> 6;
    const int lane = tid & 63;
    const int ln16 = lane & 15;
    const int quad = lane >> 4;
    const int wy = wid >> 1;
    const int wx = wid & 1;

    f32x4 acc[4][4];
    #pragma unroll
    for (int i = 0; i < 4; ++i)
        #pragma unroll
        for (int j = 0; j < 4; ++j)
            acc[i][j] = f32x4{0.f, 0.f, 0.f, 0.f};

    for (int k0 = 0; k0 < K; k0 += 32) {
        #pragma unroll
        for (int r = 0; r < 2; ++r) {
            int flat = tid + r * 256;
            int kk = flat >> 4;
            int nn = (flat & 15) * 8;
            uint4 v = *(const uint4*)(Xb + (size_t)(k0 + kk) * NP + n0 + nn);
            *(uint4*)(&Bs[kk][nn]) = v;
        }
        __syncthreads();

        bf16x8 afr[4];
        #pragma unroll
        for (int mt = 0; mt < 4; ++mt) {
            int m = m0 + wy * 64 + mt * 16 + ln16;
            uint4 v = *(const uint4*)(W + (size_t)m * K + k0 + quad * 8);
            afr[mt] = *(bf16x8*)&v;
        }
        bf16x8 bfr[4];
        #pragma unroll
        for (int nt = 0; nt < 4; ++nt) {
            int n = wx * 64 + nt * 16 + ln16;
            union { bf16x8 v; unsigned short u[8]; } tmp;
            #pragma unroll
            for (int j = 0; j < 8; ++j) tmp.u[j] = Bs[quad * 8 + j][n];
            bfr[nt] = tmp.v;
        }
        #pragma unroll
        for (int mt = 0; mt < 4; ++mt)
            #pragma unroll
            for (int nt = 0; nt < 4; ++nt)
                acc[mt][nt] = __builtin_amdgcn_mfma_f32_16x16x32_bf16(
                    afr[mt], bfr[nt], acc[mt][nt], 0, 0, 0);
        __syncthreads();
    }

    size_t outbase = (size_t)b * Cout * NP;
    #pragma unroll
    for (int mt = 0; mt < 4; ++mt) {
        #pragma unroll
        for (int nt = 0; nt < 4; ++nt) {
            int co0 = m0 + wy * 64 + mt * 16 + quad * 4;
            int n = n0 + wx * 64 + nt * 16 + ln16;
            #pragma unroll
            for (int r = 0; r < 4; ++r) {
                float v = acc[mt][nt][r];
                size_t idx = outbase + (size_t)(co0 + r) * NP + n;
                if (EPI == 0) ((unsigned short*)Out)[idx] = f2b(v);
                else          ((float*)Out)[idx] = Res[idx] + v;
            }
        }
    }
}

// ---------- depthwise 3x3, SAME: 8 px/thread, halos via shuffles ----------
__global__ __launch_bounds__(256)
void dwconv3_kernel(const unsigned short* __restrict__ in,
                    const unsigned short* __restrict__ w9,
                    unsigned short* __restrict__ out, int CH)
{
    int t = blockIdx.x * 256 + threadIdx.x;   // nb*CH*NP/8 threads
    int xi = (t & 15) * 8;
    int y  = (t >> 4) & 127;
    int bc = t >> 11;
    int c  = bc % CH;
    const unsigned short* base = in + (size_t)bc * NP + y * 128 + xi;

    float wr[9];
    #pragma unroll
    for (int i = 0; i < 9; ++i) wr[i] = b2f(w9[c * 9 + i]);

    uint4 rv0 = uint4{0,0,0,0}, rv1, rv2 = uint4{0,0,0,0};
    if (y > 0)   rv0 = *(const uint4*)(base - 128);
    rv1 = *(const uint4*)(base);
    if (y < 127) rv2 = *(const uint4*)(base + 128);
    uint4 rows[3] = {rv0, rv1, rv2};

    float o[8];
    #pragma unroll
    for (int j = 0; j < 8; ++j) o[j] = 0.f;

    #pragma unroll
    for (int r = 0; r < 3; ++r) {
        union { uint4 v; unsigned short u[8]; } cv; cv.v = rows[r];
        int lh = __shfl_up((int)cv.u[7], 1, 16);
        int rh = __shfl_down((int)cv.u[0], 1, 16);
        float p[10];
        p[0] = (xi > 0)   ? b2f((unsigned short)lh) : 0.f;
        p[9] = (xi < 120) ? b2f((unsigned short)rh) : 0.f;
        #pragma unroll
        for (int j = 0; j < 8; ++j) p[j + 1] = b2f(cv.u[j]);
        #pragma unroll
        for (int j = 0; j < 8; ++j)
            o[j] += wr[r * 3] * p[j] + wr[r * 3 + 1] * p[j + 1] + wr[r * 3 + 2] * p[j + 2];
    }
    union { uint4 v; unsigned short u[8]; } res;
    #pragma unroll
    for (int j = 0; j < 8; ++j) res.u[j] = f2b(o[j]);
    *(uint4*)(out + (size_t)bc * NP + y * 128 + xi) = res.v;
}

// ---------- fused dw3x3 + fast-GELU gate ----------
__global__ __launch_bounds__(256)
void dwgelu_kernel(const unsigned short* __restrict__ hdn,
                   const unsigned short* __restrict__ w9,
                   unsigned short* __restrict__ g)
{
    int t = blockIdx.x * 256 + threadIdx.x;   // nb*256*NP/8 threads
    int xi = (t & 15) * 8;
    int y  = (t >> 4) & 127;
    int bc = t >> 11;
    int c  = bc & 255;
    int b  = bc >> 8;
    const unsigned short* base1 = hdn + ((size_t)b * 512 + c) * NP + y * 128 + xi;
    const unsigned short* base2 = base1 + (size_t)256 * NP;

    float w1[9], w2[9];
    #pragma unroll
    for (int i = 0; i < 9; ++i) {
        w1[i] = b2f(w9[c * 9 + i]);
        w2[i] = b2f(w9[(c + 256) * 9 + i]);
    }

    uint4 ra0 = uint4{0,0,0,0}, ra1, ra2 = uint4{0,0,0,0};
    uint4 rb0 = uint4{0,0,0,0}, rb1, rb2 = uint4{0,0,0,0};
    if (y > 0)   { ra0 = *(const uint4*)(base1 - 128); rb0 = *(const uint4*)(base2 - 128); }
    ra1 = *(const uint4*)(base1);
    rb1 = *(const uint4*)(base2);
    if (y < 127) { ra2 = *(const uint4*)(base1 + 128); rb2 = *(const uint4*)(base2 + 128); }
    uint4 rowsA[3] = {ra0, ra1, ra2};
    uint4 rowsB[3] = {rb0, rb1, rb2};

    float a1[8], a2[8];
    #pragma unroll
    for (int j = 0; j < 8; ++j) { a1[j] = 0.f; a2[j] = 0.f; }

    #pragma unroll
    for (int r = 0; r < 3; ++r) {
        union { uint4 v; unsigned short u[8]; } c1, c2;
        c1.v = rowsA[r]; c2.v = rowsB[r];
        int lh1 = __shfl_up((int)c1.u[7], 1, 16);
        int rh1 = __shfl_down((int)c1.u[0], 1, 16);
        int lh2 = __shfl_up((int)c2.u[7], 1, 16);
        int rh2 = __shfl_down((int)c2.u[0], 1, 16);
        float p1[10], p2[10];
        p1[0] = (xi > 0)   ? b2f((unsigned short)lh1) : 0.f;
        p1[9] = (xi < 120) ? b2f((unsigned short)rh1) : 0.f;
        p2[0] = (xi > 0)   ? b2f((unsigned short)lh2) : 0.f;
        p2[9] = (xi < 120) ? b2f((unsigned short)rh2) : 0.f;
        #pragma unroll
        for (int j = 0; j < 8; ++j) { p1[j + 1] = b2f(c1.u[j]); p2[j + 1] = b2f(c2.u[j]); }
        #pragma unroll
        for (int j = 0; j < 8; ++j) {
            a1[j] += w1[r * 3] * p1[j] + w1[r * 3 + 1] * p1[j + 1] + w1[r * 3 + 2] * p1[j + 2];
            a2[j] += w2[r * 3] * p2[j] + w2[r * 3 + 1] * p2[j + 1] + w2[r * 3 + 2] * p2[j + 2];
        }
    }
    union { uint4 v; unsigned short u[8]; } res;
    #pragma unroll
    for (int j = 0; j < 8; ++j) {
        float u = a1[j];
        float tt = u * (0.7978845608f + 0.0356774081f * u * u);
        float e = __expf(2.f * tt);
        float th = 1.f - 2.f / (e + 1.f);
        float ge = 0.5f * u * (1.f + th);
        res.u[j] = f2b(ge * a2[j]);
    }
    *(uint4*)(g + (size_t)bc * NP + y * 128 + xi) = res.v;
}

// ---------- Gram partials + fused per-channel sumsq partials ----------
// Spart[b,h,slot,dq,dk], slot = sp*4+wid; Npart[b,h,sp, 0..15=q ch, 16..31=k ch]
__global__ __launch_bounds__(256)
void gramss_kernel(const unsigned short* __restrict__ qkv,
                   float* __restrict__ Spart, float* __restrict__ Npart)
{
    int h = blockIdx.x, b = blockIdx.y, sp = blockIdx.z;   // sp: 0..7
    int wid = threadIdx.x >> 6, lane = threadIdx.x & 63;
    int ln16 = lane & 15, quad = lane >> 4;
    int nbase = sp * 2048 + wid * 512;
    const unsigned short* qp = qkv + ((size_t)b * 384 + h * 16 + ln16) * NP;
    const unsigned short* kp = qkv + ((size_t)b * 384 + 128 + h * 16 + ln16) * NP;
    f32x4 acc = f32x4{0.f, 0.f, 0.f, 0.f};
    float qs = 0.f, ks = 0.f;
    for (int i = 0; i < 512; i += 32) {
        int n = nbase + i + quad * 8;
        uint4 av = *(const uint4*)(qp + n);
        uint4 bv = *(const uint4*)(kp + n);
        union { uint4 v; unsigned short u[8]; } ua, ub;
        ua.v = av; ub.v = bv;
        #pragma unroll
        for (int j = 0; j < 8; ++j) {
            float qv = b2f(ua.u[j]); qs += qv * qv;
            float kv = b2f(ub.u[j]); ks += kv * kv;
        }
        acc = __builtin_amdgcn_mfma_f32_16x16x32_bf16(*(bf16x8*)&av, *(bf16x8*)&bv, acc, 0, 0, 0);
    }
    int bh = b * NH + h;
    float* Sp = Spart + ((size_t)bh * 32 + sp * 4 + wid) * 256;
    #pragma unroll
    for (int r = 0; r < 4; ++r)
        Sp[(quad * 4 + r) * 16 + ln16] = acc[r];

    qs += __shfl_xor(qs, 16, 64); qs += __shfl_xor(qs, 32, 64);
    ks += __shfl_xor(ks, 16, 64); ks += __shfl_xor(ks, 32, 64);
    __shared__ float G[4][32];
    if (quad == 0) { G[wid][ln16] = qs; G[wid][16 + ln16] = ks; }
    __syncthreads();
    if (threadIdx.x < 32) {
        float s = G[0][threadIdx.x] + G[1][threadIdx.x] + G[2][threadIdx.x] + G[3][threadIdx.x];
        Npart[((size_t)bh * 8 + sp) * 32 + threadIdx.x] = s;
    }
}

// ---------- softmax over dk of (sum Spart)/(nq*nk)*temp; norms from Npart ----------
__global__ __launch_bounds__(256)
void softmax2_kernel(const float* __restrict__ Spart, const float* __restrict__ Npart,
                     const unsigned short* __restrict__ temp, float* __restrict__ P)
{
    int bh = blockIdx.x;
    int h = bh & 7;
    int t = threadIdx.x;            // 256 = 16x16
    int dq = t >> 4, dk = t & 15;
    float sacc = 0.f;
    const float* Sp = Spart + (size_t)bh * 32 * 256;
    #pragma unroll
    for (int j = 0; j < 32; ++j) sacc += Sp[j * 256 + t];
    const float* Np = Npart + (size_t)bh * 8 * 32;
    float sq = 0.f, sk = 0.f;
    #pragma unroll
    for (int sp = 0; sp < 8; ++sp) { sq += Np[sp * 32 + dq]; sk += Np[sp * 32 + 16 + dk]; }
    float nq = fmaxf(sqrtf(sq), 1e-12f);
    float nk = fmaxf(sqrtf(sk), 1e-12f);
    float v = sacc / (nq * nk) * b2f(temp[h]);
    float m = v;
    #pragma unroll
    for (int o = 8; o > 0; o >>= 1) m = fmaxf(m, __shfl_xor(m, o, 16));
    float e = __expf(v - m);
    float s = e;
    #pragma unroll
    for (int o = 8; o > 0; o >>= 1) s += __shfl_xor(s, o, 16);
    P[(size_t)bh * 256 + t] = e / s;
}

// ---------- out[b, h*16+dq, n..n+3] = sum_e P[dq,e] * v[e,n..n+3] ----------
__global__ __launch_bounds__(256)
void attnv_kernel(const float* __restrict__ P, const unsigned short* __restrict__ qkv,
                  unsigned short* __restrict__ out)
{
    __shared__ float Ps[256];
    int h = blockIdx.y, b = blockIdx.z;
    Ps[threadIdx.x] = P[((size_t)b * NH + h) * 256 + threadIdx.x];
    __syncthreads();
    int n = (blockIdx.x * 256 + threadIdx.x) * 4;     // grid.x = NP/1024
    const unsigned short* vp = qkv + ((size_t)b * 384 + 256 + h * 16) * NP + n;
    float o[16][4];
    #pragma unroll
    for (int d = 0; d < 16; ++d)
        #pragma unroll
        for (int j = 0; j < 4; ++j) o[d][j] = 0.f;
    #pragma unroll
    for (int e = 0; e < 16; ++e) {
        union { uint2 v; unsigned short u[4]; } cv;
        cv.v = *(const uint2*)(vp + (size_t)e * NP);
        float v0 = b2f(cv.u[0]), v1 = b2f(cv.u[1]), v2 = b2f(cv.u[2]), v3 = b2f(cv.u[3]);
        #pragma unroll
        for (int d = 0; d < 16; ++d) {
            float p = Ps[d * 16 + e];
            o[d][0] += p * v0; o[d][1] += p * v1; o[d][2] += p * v2; o[d][3] += p * v3;
        }
    }
    unsigned short* op = out + ((size_t)b * C + h * 16) * NP + n;
    #pragma unroll
    for (int d = 0; d < 16; ++d) {
        union { uint2 v; unsigned short u[4]; } res;
        #pragma unroll
        for (int j = 0; j < 4; ++j) res.u[j] = f2b(o[d][j]);
        *(uint2*)(op + (size_t)d * NP) = res.v;
    }
}

// ---------- pipeline ----------
struct Bufs {
    float* xmid;            // nb*C*NP fp32 (trunk after MDTA)
    unsigned short* y;      // nb*C*NP bf16 (MDTA attn out)
    unsigned short* y2;     // nb*C*NP bf16 (LN2 out)
    unsigned short* big;    // nb*512*NP bf16 (qkv1 / hdn)
    unsigned short* mid;    // nb*384*NP bf16 (qkv2 / gate out)
    float* Spart;           // nb*NH*32*256
    float* P;               // nb*NH*256
    float* Npart;           // nb*NH*8*32
};

static void run_pipeline(const float* x_f32, float* out_f32,
                         const unsigned short* w,    // packed bf16 weights
                         const Bufs& B, int nb, hipStream_t stream)
{
    const unsigned short* ln1_w   = w + 0;
    const unsigned short* ln1_b   = w + 128;
    const unsigned short* temp    = w + 256;
    const unsigned short* qkv_p_w = w + 272;
    const unsigned short* qkv_d_w = w + 49424;
    const unsigned short* proj_w  = w + 52880;
    const unsigned short* ln2_w   = w + 69264;
    const unsigned short* ln2_b   = w + 69392;
    const unsigned short* g1_w    = w + 69520;
    const unsigned short* gd_w    = w + 135056;
    const unsigned short* g2_w    = w + 139664;

    // ---- MDTA ----
    lngemm_kernel<384><<<dim3(NP / 128, nb), 256, 0, stream>>>(x_f32, ln1_w, ln1_b, qkv_p_w, B.big);
    dwconv3_kernel<<<nb * 384 * NP / 2048, 256, 0, stream>>>(B.big, qkv_d_w, B.mid, 384);
    gramss_kernel<<<dim3(NH, nb, 8), 256, 0, stream>>>(B.mid, B.Spart, B.Npart);
    softmax2_kernel<<<nb * NH, 256, 0, stream>>>(B.Spart, B.Npart, temp, B.P);
    attnv_kernel<<<dim3(NP / 1024, NH, nb), 256, 0, stream>>>(B.P, B.mid, B.y);
    projln_kernel<<<dim3(NP / 128, nb), 256, 0, stream>>>(proj_w, B.y, x_f32, B.xmid, ln2_w, ln2_b, B.y2);

    // ---- GDFN ----
    gemm_bf16_kernel<512><<<dim3(NP / 128, nb), 256, 0, stream>>>(g1_w, B.y2, B.big);
    dwgelu_kernel<<<nb * 256 * NP / 2048, 256, 0, stream>>>(B.big, gd_w, B.mid);
    gemm_pconv<256, 1><<<dim3(NP / 128, 1, nb), 256, 0, stream>>>(g2_w, B.mid, out_f32, B.xmid, 128);
}

extern "C" void kernel_launch(void* const* d_in, const int* in_sizes, int n_in,
                              void* d_out, int out_size, void* d_ws, size_t ws_size,
                              hipStream_t stream)
{
    (void)in_sizes; (void)n_in; (void)out_size;
    const float* x = (const float*)d_in[0];
    char* ws = (char*)d_ws;

    size_t off = 0;
    unsigned short* wpack = (unsigned short*)(ws + off);
    off += (size_t)kWTotal * 2;
    off = (off + 255) & ~(size_t)255;
    size_t header = off;

    auto layout = [&](int nb, size_t o, Bufs& B) -> size_t {
        B.xmid = (float*)(ws + o);           o += (size_t)nb * C * NP * 4;
        B.y    = (unsigned short*)(ws + o);  o += (size_t)nb * C * NP * 2;
        B.y2   = (unsigned short*)(ws + o);  o += (size_t)nb * C * NP * 2;
        B.big  = (unsigned short*)(ws + o);  o += (size_t)nb * 512 * NP * 2;
        B.mid  = (unsigned short*)(ws + o);  o += (size_t)nb * 384 * NP * 2;
        B.Spart = (float*)(ws + o);          o += (size_t)nb * NH * 32 * 256 * 4;
        B.P     = (float*)(ws + o);          o += (size_t)nb * NH * 256 * 4;
        B.Npart = (float*)(ws + o);          o += (size_t)nb * NH * 8 * 32 * 4;
        return o;
    };

    // ---- convert weights fp32 -> packed bf16 ----
    Ptr11 P;
    for (int i = 0; i < 11; ++i) P.p[i] = (const float*)d_in[i + 1];
    cvt_w_kernel<<<dim3(256, 11), 256, 0, stream>>>(P, wpack);

    Bufs Bfull;
    size_t need_full = layout(4, header, Bfull);

    if (ws_size >= need_full) {
        run_pipeline(x, (float*)d_out, wpack, Bfull, 4, stream);
    } else {
        Bufs B1;
        layout(1, header, B1);
        for (int b = 0; b < 4; ++b) {
            run_pipeline(x + (size_t)b * C * NP,
                         (float*)d_out + (size_t)b * C * NP,
                         wpack, B1, 1, stream);
        }
    }
}